// Round 1
// 1139.716 us; speedup vs baseline: 1.0097x; 1.0097x over previous
//
#include <hip/hip_runtime.h>

// Problem constants (from reference setup_inputs):
//   T = 8192 tokens, H = 4096 hidden, E = 64 experts, K = 2 top-k, D = 8 devices
// Output: [D, T, H] float32 -- out[d,t,:] = mask(d,t) ? input[t,:] : 0
// mask(d,t) = any_k( expert_mapping[expert_indices[t,k]] == d )
//
// Structure (v2): the mask hit-rate is only ~23% (1 - (7/8)^2), so 77% of the
// 1 GiB output is zeros. Hand-writing those zeros with nontemporal stores in
// 64Ki one-row blocks measured far below the fill-path ceiling; the runtime's
// fillBufferAligned is *measured* at 6.29 TB/s (78% peak) on this chip in this
// very capture. So:
//   pass 1: hipMemsetAsync(out, 0)          -- 1.074 GB at fill speed (~170us)
//   pass 2: copy only hit rows (t,k)-indexed -- ~240 MiB R + ~240 MiB W (~80us)
// Hit rows are overwritten once (zero then data) costing +240 MiB of writes,
// but both passes ride proven-full-BW store paths.

#define T_TOK 8192
#define H_DIM 4096
#define NUM_DEV 8
#define TOPK 2

typedef float vfloat4 __attribute__((ext_vector_type(4)));

// One block per (t, k) pair: 16384 blocks, 256 threads, 4 x float4 per thread
// = one 16 KiB row copy. k==1 block exits when its device duplicates k==0's
// (same expert twice, or two experts on one device) so no row is copied twice.
// Plain (cached) stores: this is the store path the 6.29 TB/s fill uses; the
// write stream here is only ~240 MiB, and input stays resident in the 256 MiB
// L3 regardless.
__global__ __launch_bounds__(256)
void a2a_copy_rows_kernel(const float* __restrict__ input,
                          const int* __restrict__ expert_indices,
                          const int* __restrict__ expert_mapping,
                          float* __restrict__ out)
{
    const unsigned bid = blockIdx.x;          // in [0, T*TOPK)
    const unsigned t   = bid >> 1;            // token
    const unsigned k   = bid & 1;             // which of the top-k slots

    // Wave-uniform scalar loads; index data (64 KiB + 256 B) is cache-resident.
    const int e   = expert_indices[TOPK * t + k];
    const int dev = expert_mapping[e];
    if (k == 1) {
        const int e0 = expert_indices[TOPK * t];
        if (expert_mapping[e0] == dev) return;   // duplicate device -> row
    }                                            // already copied by k==0 block

    const vfloat4* __restrict__ in_row =
        (const vfloat4*)(input + (size_t)t * H_DIM);
    vfloat4* __restrict__ out_row =
        (vfloat4*)(out + ((size_t)dev * T_TOK + (size_t)t) * H_DIM);

#pragma unroll
    for (int i = 0; i < 4; ++i) {
        out_row[threadIdx.x + i * 256] = in_row[threadIdx.x + i * 256];
    }
}

extern "C" void kernel_launch(void* const* d_in, const int* in_sizes, int n_in,
                              void* d_out, int out_size, void* d_ws, size_t ws_size,
                              hipStream_t stream) {
    const float* input          = (const float*)d_in[0];   // [T, H] fp32
    const int*   expert_indices = (const int*)d_in[1];     // [T, K] int32
    const int*   expert_mapping = (const int*)d_in[2];     // [E]    int32
    float*       out            = (float*)d_out;           // [D, T, H] fp32

    // Pass 1: zero the whole output on the runtime's fill path (6.29 TB/s
    // measured). Stream-ordered + graph-capturable.
    const size_t out_bytes = (size_t)NUM_DEV * T_TOK * H_DIM * sizeof(float);
    hipMemsetAsync(out, 0, out_bytes, stream);

    // Pass 2: copy the ~15.4K hit rows over the zero bed.
    const int grid = T_TOK * TOPK;   // 16384 blocks, <=1 row each
    a2a_copy_rows_kernel<<<grid, 256, 0, stream>>>(input, expert_indices,
                                                   expert_mapping, out);
}

// Round 2
// 1136.628 us; speedup vs baseline: 1.0125x; 1.0027x over previous
//
#include <hip/hip_runtime.h>

// Problem constants (from reference setup_inputs):
//   T = 8192 tokens, H = 4096 hidden, E = 64 experts, K = 2 top-k, D = 8 devices
// Output: [D, T, H] float32 -- out[d,t,:] = mask(d,t) ? input[t,:] : 0
// mask(d,t) = any_k( expert_mapping[expert_indices[t,k]] == d )
//
// v3 structure: ONE PASS, one block per token, mandatory-traffic-only.
//   - dur_us is dominated by a fixed ~850us harness re-poison (4.3 GB
//     fillBufferAligned visible once per iteration in rocprof); our
//     controllable portion is just the kernel work.
//   - Mandatory traffic: 1.074 GB writes (poison garbage -> every output byte
//     must be written, zeros included) + 0.128 GB reads (each input row once).
//   - Round-1's memset+copy moved 1.57 GB (hit rows written twice); round-0's
//     fused kernel moved 1.31 GB (hit rows read ~1.875x, NT stores). This
//     version moves exactly 1.20 GB: each block reads its row into registers
//     ONCE and writes all 8 device slices (data or zeros) with plain cached
//     stores -- the same store path fillBufferAligned uses at 6.29 TB/s.
//   - Device mask is block-uniform -> the per-device hit branch is wave-uniform
//     (s_cbranch, no divergence, no per-element cndmask).

#define T_TOK 8192
#define H_DIM 4096
#define NUM_DEV 8
#define TOPK 2

typedef float vfloat4 __attribute__((ext_vector_type(4)));

__global__ __launch_bounds__(256)
void a2a_dispatch_rowcast(const float* __restrict__ input,
                          const int* __restrict__ expert_indices,
                          const int* __restrict__ expert_mapping,
                          float* __restrict__ out)
{
    const unsigned t = blockIdx.x;            // one block per token, t in [0,T)

    // Wave-uniform scalar loads; index data (64 KiB + 256 B) is cache-resident.
    const int e0 = expert_indices[TOPK * t];
    const int e1 = expert_indices[TOPK * t + 1];
    const unsigned mask =
        (1u << expert_mapping[e0]) | (1u << expert_mapping[e1]);

    // Load the 16 KiB token row into registers exactly once.
    // 256 threads x 4 x float4 = 4096 floats.
    const vfloat4* __restrict__ in_row =
        (const vfloat4*)(input + (size_t)t * H_DIM);
    const vfloat4 v0 = in_row[threadIdx.x];
    const vfloat4 v1 = in_row[threadIdx.x + 256];
    const vfloat4 v2 = in_row[threadIdx.x + 512];
    const vfloat4 v3 = in_row[threadIdx.x + 768];
    const vfloat4 z  = (vfloat4)(0.f);

    // Write all 8 device slices: row data on hit, zeros on miss.
    vfloat4* out_row = (vfloat4*)(out + (size_t)t * H_DIM);
    const size_t slice_v4 = (size_t)T_TOK * (H_DIM / 4);   // device-slice stride
#pragma unroll
    for (int d = 0; d < NUM_DEV; ++d) {
        if ((mask >> d) & 1u) {       // block-uniform branch
            out_row[threadIdx.x      ] = v0;
            out_row[threadIdx.x + 256] = v1;
            out_row[threadIdx.x + 512] = v2;
            out_row[threadIdx.x + 768] = v3;
        } else {
            out_row[threadIdx.x      ] = z;
            out_row[threadIdx.x + 256] = z;
            out_row[threadIdx.x + 512] = z;
            out_row[threadIdx.x + 768] = z;
        }
        out_row += slice_v4;
    }
}

extern "C" void kernel_launch(void* const* d_in, const int* in_sizes, int n_in,
                              void* d_out, int out_size, void* d_ws, size_t ws_size,
                              hipStream_t stream) {
    const float* input          = (const float*)d_in[0];   // [T, H] fp32
    const int*   expert_indices = (const int*)d_in[1];     // [T, K] int32
    const int*   expert_mapping = (const int*)d_in[2];     // [E]    int32
    float*       out            = (float*)d_out;           // [D, T, H] fp32

    a2a_dispatch_rowcast<<<T_TOK, 256, 0, stream>>>(input, expert_indices,
                                                    expert_mapping, out);
}